// Round 11
// baseline (2198.230 us; speedup 1.0000x reference)
//
#include <hip/hip_runtime.h>

#define D 64
#define BLK 256

#define NBSHIFT 7
#define NPB 128                        // nodes per bucket
#define NBMAX 1024                     // bucket table size (N <= 131072)
#define TA 4096                        // edges per binA tile

typedef unsigned int uint32;
typedef unsigned short ushort16;
typedef __attribute__((ext_vector_type(8))) short bf16x8;
typedef __attribute__((ext_vector_type(4))) float f32x4;

// ---- bf16 helpers (RTNE) ----
__device__ inline uint32 f2bf_u(float f) {
    uint32 u = __float_as_uint(f);
    u += 0x7FFFu + ((u >> 16) & 1u);
    return u >> 16;
}

// ---------------- fused prep: hist(1024) | cvt | wf ----------------
__global__ void prep_kernel(const int* __restrict__ row, uint32* __restrict__ bcount,
                            const float* __restrict__ x, uint2* __restrict__ xb,
                            const float* __restrict__ W, uint4* __restrict__ Wf,
                            int E, int n4, int gTile, int gCvt) {
    int bid = blockIdx.x;
    int tid = threadIdx.x;
    if (bid < gTile) {
        __shared__ uint32 h[NBMAX];
        for (int i = tid; i < NBMAX; i += 256) h[i] = 0;
        __syncthreads();
        int base = bid * TA;
        int end = min(base + TA, E);
        for (int e = base + tid; e < end; e += 256)
            atomicAdd(&h[(uint32)row[e] >> NBSHIFT], 1u);
        __syncthreads();
        for (int i = tid; i < NBMAX; i += 256)
            if (h[i]) atomicAdd(&bcount[i], h[i]);
    } else if (bid < gTile + gCvt) {
        int i = (bid - gTile) * 256 + tid;
        if (i < n4) {
            float4 v = ((const float4*)x)[i];
            uint2 pack;
            pack.x = f2bf_u(v.x) | (f2bf_u(v.y) << 16);
            pack.y = f2bf_u(v.z) | (f2bf_u(v.w) << 16);
            xb[i] = pack;
        }
    } else {
        int t2 = (bid - gTile - gCvt) * 256 + tid;   // 0..2047
        int l = t2 & 63;
        int g = t2 >> 6;       // 0..31
        int kh = g & 1;
        int t = (g >> 1) & 3;
        int w = g >> 3;
        int n = t * 16 + (l & 15);
        int kbase = kh * 32 + (l >> 4) * 8;
        uint32 pk[4];
        #pragma unroll
        for (int i = 0; i < 4; ++i) {
            int k0 = kbase + 2 * i, k1 = k0 + 1;
            float v0 = W[(size_t)w * 4096 + (size_t)k0 * 64 + n];
            float v1 = W[(size_t)w * 4096 + (size_t)k1 * 64 + n];
            pk[i] = f2bf_u(v0) | (f2bf_u(v1) << 16);
        }
        Wf[t2] = make_uint4(pk[0], pk[1], pk[2], pk[3]);
    }
}

// ---------------- scan of 1024 bucket counts -> gcursor (mutable) + bbase (stable) ----------------
__global__ void scan1024_kernel(const uint32* __restrict__ bcount, uint32* __restrict__ gcursor,
                                uint32* __restrict__ bbase, int E) {
    __shared__ uint32 ps[256];
    int tid = threadIdx.x;
    uint32 v[4];
    uint32 s = 0;
    #pragma unroll
    for (int i = 0; i < 4; ++i) { v[i] = bcount[tid * 4 + i]; s += v[i]; }
    ps[tid] = s;
    __syncthreads();
    for (int off = 1; off < 256; off <<= 1) {
        uint32 t = (tid >= off) ? ps[tid - off] : 0u;
        __syncthreads();
        ps[tid] += t;
        __syncthreads();
    }
    uint32 run = ps[tid] - s;
    #pragma unroll
    for (int i = 0; i < 4; ++i) {
        gcursor[tid * 4 + i] = run;
        bbase[tid * 4 + i] = run;
        run += v[i];
    }
    if (tid == 255) bbase[NBMAX] = (uint32)E;
}

// ---------------- pass A: bin (rowlocal(7b)<<17 | col(17b), attr) by 128-node bucket ----------------
__global__ void binA_kernel(const int* __restrict__ row, const int* __restrict__ col,
                            const float* __restrict__ attr,
                            uint32* __restrict__ gcursor, int2* __restrict__ binned, int E) {
    __shared__ uint32 hist[NBMAX], lstart[NBMAX], lcur[NBMAX], baseg[NBMAX];
    __shared__ uint32 ps[256];
    __shared__ int2 stage[TA];
    __shared__ ushort16 sbkt[TA];
    int tid = threadIdx.x;
    int tile = blockIdx.x * TA;
    for (int i = tid; i < NBMAX; i += 256) hist[i] = 0;
    __syncthreads();

    uint32 px[16], py[16], bk[16];
    #pragma unroll
    for (int k = 0; k < 16; ++k) {
        int e = tile + k * 256 + tid;
        bk[k] = 0xFFFFFFFFu;
        if (e < E) {
            int r = row[e], c = col[e];
            uint32 b = (uint32)r >> NBSHIFT;
            bk[k] = b;
            px[k] = ((uint32)(r & (NPB - 1)) << 17) | (uint32)c;
            py[k] = __float_as_uint(attr[e]);
            atomicAdd(&hist[b], 1u);
        }
    }
    __syncthreads();
    // scan over 1024 via 4-per-thread serial + 256 Hillis-Steele
    uint32 v4[4];
    uint32 s = 0;
    #pragma unroll
    for (int i = 0; i < 4; ++i) { v4[i] = hist[tid * 4 + i]; s += v4[i]; }
    ps[tid] = s;
    __syncthreads();
    for (int off = 1; off < 256; off <<= 1) {
        uint32 t = (tid >= off) ? ps[tid - off] : 0u;
        __syncthreads();
        ps[tid] += t;
        __syncthreads();
    }
    uint32 run = ps[tid] - s;
    #pragma unroll
    for (int i = 0; i < 4; ++i) {
        uint32 idx = tid * 4 + i;
        lstart[idx] = run;
        lcur[idx] = run;
        baseg[idx] = v4[i] ? atomicAdd(&gcursor[idx], v4[i]) : 0u;
        run += v4[i];
    }
    __syncthreads();
    #pragma unroll
    for (int k = 0; k < 16; ++k) {
        if (bk[k] != 0xFFFFFFFFu) {
            uint32 pos = atomicAdd(&lcur[bk[k]], 1u);
            stage[pos] = make_int2((int)px[k], (int)py[k]);
            sbkt[pos] = (ushort16)bk[k];
        }
    }
    __syncthreads();
    int cnt = min(TA, E - tile);
    for (int i = tid; i < cnt; i += 256) {
        uint32 b = sbkt[i];
        uint32 dst = baseg[b] + (uint32)i - lstart[b];
        binned[dst] = stage[i];
    }
}

// ---------------- per-bucket: degree -> dinv; gx = dinv (.) xb ----------------
__global__ void dinvgx_kernel(const int2* __restrict__ binned, const uint32* __restrict__ bbase,
                              const uint2* __restrict__ xb, uint2* __restrict__ gx,
                              float* __restrict__ dinv, int N) {
    __shared__ uint32 cnt[NPB];
    __shared__ float ld[NPB];
    int b = blockIdx.x;
    int tid = threadIdx.x;
    if (tid < NPB) cnt[tid] = 0;
    __syncthreads();
    uint32 start = bbase[b], end = bbase[b + 1];
    for (uint32 i = start + tid; i < end; i += 256)
        atomicAdd(&cnt[(uint32)binned[i].x >> 17], 1u);
    __syncthreads();
    if (tid < NPB) {
        int node = b * NPB + tid;
        float d = (node < N && cnt[tid]) ? rsqrtf((float)cnt[tid]) : 0.0f;
        ld[tid] = d;
        if (node < N) dinv[node] = d;
    }
    __syncthreads();
    for (int i = tid; i < NPB * 16; i += 256) {
        int r = i >> 4;
        int node = b * NPB + r;
        if (node >= N) continue;
        uint2 v = xb[(size_t)node * 16 + (i & 15)];
        float sc = ld[r];
        float f0 = __uint_as_float(v.x << 16) * sc;
        float f1 = __uint_as_float(v.x & 0xFFFF0000u) * sc;
        float f2 = __uint_as_float(v.y << 16) * sc;
        float f3 = __uint_as_float(v.y & 0xFFFF0000u) * sc;
        uint2 o;
        o.x = f2bf_u(f0) | (f2bf_u(f1) << 16);
        o.y = f2bf_u(f2) | (f2bf_u(f3) << 16);
        gx[(size_t)node * 16 + (i & 15)] = o;
    }
}

// ---------------- LDS-accumulator SpMM: one block per 128-node bucket ----------------
// acc[rl][c] += attr_e * g[col_e][c]; T[n] = scale*(-dinv_n*acc[n]) - prev[n]; gout = dinv_n*T[n]
__global__ void spmm_lds_kernel(const int2* __restrict__ binned, const uint32* __restrict__ bbase,
                                const char* __restrict__ gin, const uint4* __restrict__ prev,
                                const float* __restrict__ dinv,
                                uint4* __restrict__ outT, uint4* __restrict__ outG,
                                float scale, int N) {
    __shared__ float acc[NPB * 64];
    int b = blockIdx.x;
    int tid = threadIdx.x;
    for (int i = tid; i < NPB * 64; i += 256) acc[i] = 0.0f;
    int lane = tid & 63;
    int w = tid >> 6;
    int q = lane >> 3;          // 8 edges per wave-iteration
    int sub = lane & 7;         // 8 bf16 cols per lane
    uint32 start = bbase[b], end = bbase[b + 1];
    __syncthreads();

    uint32 e0 = start + (uint32)w * 8;
    if (e0 < end) {
        // software pipeline: prefetch next octet while consuming current
        uint32 e = e0 + q;
        bool act = e < end;
        int2 rec = binned[act ? e : end - 1];
        uint4 h = *(const uint4*)(gin + ((((uint32)rec.x) & 0x1FFFFu) << 7) + sub * 16);
        for (e0 += 32;; e0 += 32) {
            bool more = e0 < end;
            int2 recn;
            uint4 hn;
            if (more) {
                uint32 en = e0 + q;
                bool actn = en < end;
                recn = binned[actn ? en : end - 1];
                hn = *(const uint4*)(gin + ((((uint32)recn.x) & 0x1FFFFu) << 7) + sub * 16);
            }
            float at = act ? __int_as_float(rec.y) : 0.0f;
            uint32 rl = (uint32)rec.x >> 17;
            float* ap = &acc[(rl << 6) + (sub << 3)];
            atomicAdd(ap + 0, at * __uint_as_float(h.x << 16));
            atomicAdd(ap + 1, at * __uint_as_float(h.x & 0xFFFF0000u));
            atomicAdd(ap + 2, at * __uint_as_float(h.y << 16));
            atomicAdd(ap + 3, at * __uint_as_float(h.y & 0xFFFF0000u));
            atomicAdd(ap + 4, at * __uint_as_float(h.z << 16));
            atomicAdd(ap + 5, at * __uint_as_float(h.z & 0xFFFF0000u));
            atomicAdd(ap + 6, at * __uint_as_float(h.w << 16));
            atomicAdd(ap + 7, at * __uint_as_float(h.w & 0xFFFF0000u));
            if (!more) break;
            rec = recn;
            h = hn;
            act = (e0 + q) < end;
        }
    }
    __syncthreads();

    // epilogue: 128 rows x 8 uint4 segments = 1024 / 256 threads = 4 each
    for (int i = tid; i < NPB * 8; i += 256) {
        int r = i >> 3;
        int seg = i & 7;
        int node = b * NPB + r;
        if (node >= N) continue;
        float dn = dinv[node];
        const float* ap = &acc[(r << 6) + (seg << 3)];
        float t[8];
        float pf[8] = {0.f, 0.f, 0.f, 0.f, 0.f, 0.f, 0.f, 0.f};
        if (prev) {
            uint4 pv = prev[(size_t)node * 8 + seg];
            pf[0] = __uint_as_float(pv.x << 16);
            pf[1] = __uint_as_float(pv.x & 0xFFFF0000u);
            pf[2] = __uint_as_float(pv.y << 16);
            pf[3] = __uint_as_float(pv.y & 0xFFFF0000u);
            pf[4] = __uint_as_float(pv.z << 16);
            pf[5] = __uint_as_float(pv.z & 0xFFFF0000u);
            pf[6] = __uint_as_float(pv.w << 16);
            pf[7] = __uint_as_float(pv.w & 0xFFFF0000u);
        }
        #pragma unroll
        for (int k = 0; k < 8; ++k)
            t[k] = scale * (-dn * ap[k]) - pf[k];
        uint4 pk;
        pk.x = f2bf_u(t[0]) | (f2bf_u(t[1]) << 16);
        pk.y = f2bf_u(t[2]) | (f2bf_u(t[3]) << 16);
        pk.z = f2bf_u(t[4]) | (f2bf_u(t[5]) << 16);
        pk.w = f2bf_u(t[6]) | (f2bf_u(t[7]) << 16);
        outT[(size_t)node * 8 + seg] = pk;
        if (outG) {
            uint4 pg;
            pg.x = f2bf_u(t[0] * dn) | (f2bf_u(t[1] * dn) << 16);
            pg.y = f2bf_u(t[2] * dn) | (f2bf_u(t[3] * dn) << 16);
            pg.z = f2bf_u(t[4] * dn) | (f2bf_u(t[5] * dn) << 16);
            pg.w = f2bf_u(t[6] * dn) | (f2bf_u(t[7] * dn) << 16);
            outG[(size_t)node * 8 + seg] = pg;
        }
    }
}

// ---------------- fused MFMA GEMM: out = bias + x@W0 + T1@W1 + T2@W2 + T3@W3 ----------------
__global__ void gemm_mfma(const uint4* __restrict__ h0, const uint4* __restrict__ h1,
                          const uint4* __restrict__ h2, const uint4* __restrict__ h3,
                          const uint4* __restrict__ Wf, const float* __restrict__ bias,
                          float* __restrict__ out, int N) {
    int tid = threadIdx.x;
    int wave = tid >> 6;
    int lane = tid & 63;
    int quad = lane >> 4;
    int lo = lane & 15;
    int m0 = blockIdx.x * 64 + wave * 16;
    int mrow = m0 + lo;
    int mclamp = min(mrow, N - 1);

    f32x4 acc[4] = {{0.f,0.f,0.f,0.f},{0.f,0.f,0.f,0.f},{0.f,0.f,0.f,0.f},{0.f,0.f,0.f,0.f}};
    const uint4* hs[4] = { h0, h1, h2, h3 };
    #pragma unroll
    for (int w = 0; w < 4; ++w) {
        union { uint4 u; bf16x8 v; } a0, a1;
        a0.u = hs[w][(size_t)mclamp * 8 + quad];       // kh = 0
        a1.u = hs[w][(size_t)mclamp * 8 + 4 + quad];   // kh = 1
        #pragma unroll
        for (int t = 0; t < 4; ++t) {
            union { uint4 u; bf16x8 v; } b0, b1;
            b0.u = Wf[(w * 8 + t * 2 + 0) * 64 + lane];
            b1.u = Wf[(w * 8 + t * 2 + 1) * 64 + lane];
            acc[t] = __builtin_amdgcn_mfma_f32_16x16x32_bf16(a0.v, b0.v, acc[t], 0, 0, 0);
            acc[t] = __builtin_amdgcn_mfma_f32_16x16x32_bf16(a1.v, b1.v, acc[t], 0, 0, 0);
        }
    }
    #pragma unroll
    for (int t = 0; t < 4; ++t) {
        int col = t * 16 + lo;
        float bv = bias[col];
        #pragma unroll
        for (int r = 0; r < 4; ++r) {
            int rowi = m0 + quad * 4 + r;
            if (rowi < N) out[(size_t)rowi * 64 + col] = acc[t][r] + bv;
        }
    }
}

extern "C" void kernel_launch(void* const* d_in, const int* in_sizes, int n_in,
                              void* d_out, int out_size, void* d_ws, size_t ws_size,
                              hipStream_t stream) {
    const float* x    = (const float*)d_in[0];
    const int*   ei   = (const int*)d_in[1];
    const float* attr = (const float*)d_in[2];
    const float* W    = (const float*)d_in[3];   // [4,64,64]
    const float* bias = (const float*)d_in[4];   // [64]
    float* out = (float*)d_out;

    const int N = in_sizes[0] / D;
    const int E = in_sizes[1] / 2;
    const int* row = ei;        // edge_index[0]
    const int* col = ei + E;    // edge_index[1]
    const int NBK = (N + NPB - 1) >> NBSHIFT;    // 128-node buckets

    // workspace layout — 16B-aligned arrays first (~78 MB)
    char* p = (char*)d_ws;
    int2*     binned  = (int2*)p;                p += (size_t)E * 8;   // persists through all spmms
    uint2*    xb      = (uint2*)p;               p += (size_t)N * D * 2;
    uint2*    bufA    = (uint2*)p;               p += (size_t)N * D * 2;  // gx -> g2
    uint2*    bufB    = (uint2*)p;               p += (size_t)N * D * 2;  // g1 -> T3
    uint2*    T1      = (uint2*)p;               p += (size_t)N * D * 2;
    uint2*    T2      = (uint2*)p;               p += (size_t)N * D * 2;
    uint4*    Wf      = (uint4*)p;               p += 2048 * 16;
    uint32*   bcount  = (uint32*)p;              p += NBMAX * 4;
    uint32*   gcursor = (uint32*)p;              p += NBMAX * 4;
    uint32*   bbase   = (uint32*)p;              p += (NBMAX + 1) * 4;
    float*    dinv    = (float*)p;               /* p += N*4 */

    const int gGm = (N + 63) / 64;
    const int gTile = (E + TA - 1) / TA;
    const int gCvt = ((N * D / 4) + 255) / 256;

    // ---- prep (hist|cvt|wf) + CSR-bucket build ----
    hipMemsetAsync(bcount, 0, NBMAX * 4, stream);
    prep_kernel<<<gTile + gCvt + 8, 256, 0, stream>>>(row, bcount, x, xb, W, Wf,
                                                      E, N * D / 4, gTile, gCvt);
    scan1024_kernel<<<1, 256, 0, stream>>>(bcount, gcursor, bbase, E);
    binA_kernel<<<gTile, 256, 0, stream>>>(row, col, attr, gcursor, binned, E);
    dinvgx_kernel<<<NBK, 256, 0, stream>>>(binned, bbase, xb, bufA, dinv, N);

    // ---- Chebyshev via LDS-accumulator SpMM (g-scheme) ----
    // T1 = S(x) = -dinv.acc(attr*gx);  g1 = dinv.T1
    spmm_lds_kernel<<<NBK, 256, 0, stream>>>(binned, bbase, (const char*)bufA, nullptr, dinv,
                                             (uint4*)T1, (uint4*)bufB, 1.0f, N);
    // T2 = 2*S(T1) - x;  g2 = dinv.T2   (bufA: gx dead)
    spmm_lds_kernel<<<NBK, 256, 0, stream>>>(binned, bbase, (const char*)bufB, (const uint4*)xb, dinv,
                                             (uint4*)T2, (uint4*)bufA, 2.0f, N);
    // T3 = 2*S(T2) - T1   (bufB: g1 dead)
    spmm_lds_kernel<<<NBK, 256, 0, stream>>>(binned, bbase, (const char*)bufA, (const uint4*)T1, dinv,
                                             (uint4*)bufB, nullptr, 2.0f, N);
    // out = bias + x@W0 + T1@W1 + T2@W2 + T3@W3
    gemm_mfma<<<gGm, BLK, 0, stream>>>((const uint4*)xb, (const uint4*)T1, (const uint4*)T2,
                                       (const uint4*)bufB, Wf, bias, out, N);
}